// Round 5
// baseline (61.410 us; speedup 1.0000x reference)
//
#include <hip/hip_runtime.h>

#define B_TOTAL 131072
#define NF 32
#define NA 8
#define NH 64

using frag_ab = __attribute__((ext_vector_type(8))) short;   // 8 bf16 (4 VGPRs)
using f32x16  = __attribute__((ext_vector_type(16))) float;  // 32x32 accumulator
typedef int   v2i __attribute__((ext_vector_type(2)));
typedef float v2f __attribute__((ext_vector_type(2)));

__device__ __forceinline__ unsigned short f2bf(float x) {
  unsigned u = __float_as_uint(x);
  u = (u + 0x7FFFu + ((u >> 16) & 1u)) >> 16;   // RNE
  return (unsigned short)u;
}

// 32x32 A-frag pack: w1p[((f*6 + ht*3 + kt)*64 + l)*8 + j]
//   h = ht*32 + (l&31), i = kt*16 + (l>>5)*8 + j
//   i<40 -> W1[f][i][h]; i==40 -> b1[f][h] (bias fold); else 0
__global__ void pack_w1_kernel(const float* __restrict__ W1, const float* __restrict__ b1,
                               unsigned short* __restrict__ w1p) {
  int idx = blockIdx.x * 256 + threadIdx.x;   // 98304 total
  int j = idx & 7, l = (idx >> 3) & 63, tq = idx >> 9;
  int q = tq % 6, f = tq / 6;
  int ht = q / 3, kt = q % 3;
  int h = ht * 32 + (l & 31);
  int i = kt * 16 + ((l >> 5) << 3) + j;
  float v = 0.0f;
  if (i < NF + NA)       v = W1[(f * (NF + NA) + i) * NH + h];
  else if (i == NF + NA) v = b1[f * NH + h];
  w1p[idx] = f2bf(v);
}

// w2p[((f*2+g)*2+ht)*16 + r] = W2[f][ht*32 + (r&3) + 8*(r>>2) + 4*g]
// (matches verified 32x32 C/D row map: row = (reg&3) + 8*(reg>>2) + 4*(lane>>5))
__global__ void pack_w2_kernel(const float* __restrict__ W2, float* __restrict__ w2p) {
  int idx = blockIdx.x * 256 + threadIdx.x;   // 4096 total
  int r = idx & 15, ht = (idx >> 4) & 1, g = (idx >> 5) & 1, f = idx >> 6;
  w2p[idx] = W2[f * NH + ht * 32 + (r & 3) + 8 * (r >> 2) + 4 * g];
}

__device__ __forceinline__ v2f pk_fma(v2f a, v2f b, v2f c) {   // 2 f32 FMAs / instr
  v2f d;
  asm("v_pk_fma_f32 %0, %1, %2, %3" : "=v"(d) : "v"(a), "v"(b), "v"(c));
  return d;
}

__device__ __forceinline__ float xor32_add(float v) {   // R4-verified lane^32 sum
  v2i p = __builtin_amdgcn_permlane32_swap(__float_as_int(v), __float_as_int(v), false, false);
  return __int_as_float(p.x) + __int_as_float(p.y);
}

__global__ __launch_bounds__(256, 2) void fused_mlp_kernel(
    const float* __restrict__ ft, const float* __restrict__ at,
    const unsigned short* __restrict__ w1p, const float* __restrict__ w2p,
    const float* __restrict__ b2, float* __restrict__ out) {
  __shared__ __align__(16) unsigned short wlds[2][12288];   // dbuf: 4 f's of frags (2 x 24KB)

  const int t = threadIdx.x;
  const int wv = t >> 6;
  const int l = t & 63;
  const int g = l >> 5;        // lane half: k-slice select / D row offset
  const int lc = l & 31;       // 32-tile column (batch)
  const long rowb = (long)blockIdx.x * 256 + wv * 64;   // wave owns 64 rows

  // ---- stage round 0 (issue first; hides under bfr build) ----
  {
    const unsigned short* src = w1p + t * 8;
#pragma unroll
    for (int k = 0; k < 6; ++k)
      __builtin_amdgcn_global_load_lds((const __attribute__((address_space(1))) void*)(src + k * 2048),
                                       (__attribute__((address_space(3))) void*)(&wlds[0][k * 2048 + t * 8]), 16, 0, 0);
  }

  // ---- B-frags (fa^T) in registers: lane holds col b = rowb + bt*32 + lc,
  //      k = kt*16 + g*8 + j  (k==40 -> bias 1.0) ----
  frag_ab bfr[2][3];
#pragma unroll
  for (int bt = 0; bt < 2; ++bt) {
    const long b = rowb + bt * 32 + lc;
    const float* fr = ft + b * NF;
    float tmp[8];
#pragma unroll
    for (int kt = 0; kt < 2; ++kt) {
      *(float4*)tmp       = *(const float4*)(fr + kt * 16 + g * 8);
      *(float4*)(tmp + 4) = *(const float4*)(fr + kt * 16 + g * 8 + 4);
      frag_ab fb;
#pragma unroll
      for (int j = 0; j < 8; ++j) fb[j] = (short)f2bf(tmp[j]);
      bfr[bt][kt] = fb;
    }
    *(float4*)tmp       = *(const float4*)(at + b * NA);
    *(float4*)(tmp + 4) = *(const float4*)(at + b * NA + 4);
    frag_ab fb;
#pragma unroll
    for (int j = 0; j < 8; ++j) {
      unsigned short bias = (j == 0) ? (unsigned short)0x3F80 : (unsigned short)0;
      fb[j] = (short)((g == 0) ? f2bf(tmp[j]) : bias);
    }
    bfr[bt][2] = fb;
  }

  const f32x16 zero16 = {0.f,0.f,0.f,0.f,0.f,0.f,0.f,0.f,0.f,0.f,0.f,0.f,0.f,0.f,0.f,0.f};
  float res[NF];   // full output row held to the end (static indexing after unroll)

  for (int r = 0; r < 8; ++r) {
    __syncthreads();   // buf[r&1] staged (barrier drains vmcnt); prev buf free

    if (r < 7) {
      const unsigned short* src = w1p + (r + 1) * 12288 + t * 8;
#pragma unroll
      for (int k = 0; k < 6; ++k)
        __builtin_amdgcn_global_load_lds((const __attribute__((address_space(1))) void*)(src + k * 2048),
                                         (__attribute__((address_space(3))) void*)(&wlds[(r + 1) & 1][k * 2048 + t * 8]), 16, 0, 0);
    }

    const unsigned short* buf = wlds[r & 1];

#pragma unroll
    for (int fo = 0; fo < 4; ++fo) {
      const int f = r * 4 + fo;

      // A-frags (W1T) for this f: 6 x ds_read_b128
      frag_ab wf[2][3];
#pragma unroll
      for (int ht = 0; ht < 2; ++ht)
#pragma unroll
        for (int kt = 0; kt < 3; ++kt)
          wf[ht][kt] = *(const frag_ab*)&buf[((fo * 6 + ht * 3 + kt) * 64 + l) * 8];

      // W2 for this lane: 8 float4 (L1-resident broadcast)
      float4 wq[8];
      const float4* wp = (const float4*)w2p + (f * 2 + g) * 8;
#pragma unroll
      for (int q = 0; q < 8; ++q) wq[q] = wp[q];

      float sb[2];
#pragma unroll
      for (int bt = 0; bt < 2; ++bt) {
        f32x16 a0 = zero16, a1 = zero16;
#pragma unroll
        for (int kt = 0; kt < 3; ++kt) {
          a0 = __builtin_amdgcn_mfma_f32_32x32x16_bf16(wf[0][kt], bfr[bt][kt], a0, 0, 0, 0);
          a1 = __builtin_amdgcn_mfma_f32_32x32x16_bf16(wf[1][kt], bfr[bt][kt], a1, 0, 0, 0);
        }
        // layer 2: relu + dot(W2) over lane's 32 h-values (pk_fma pairs, 2 chains)
        v2f ps0 = {0.f, 0.f}, ps1 = {0.f, 0.f};
#pragma unroll
        for (int rq = 0; rq < 4; ++rq) {
          float4 w0 = wq[rq], w1 = wq[4 + rq];
          v2f m;
          m[0] = fmaxf(a0[rq * 4 + 0], 0.f); m[1] = fmaxf(a0[rq * 4 + 1], 0.f);
          ps0 = pk_fma(m, (v2f){w0.x, w0.y}, ps0);
          m[0] = fmaxf(a0[rq * 4 + 2], 0.f); m[1] = fmaxf(a0[rq * 4 + 3], 0.f);
          ps0 = pk_fma(m, (v2f){w0.z, w0.w}, ps0);
          m[0] = fmaxf(a1[rq * 4 + 0], 0.f); m[1] = fmaxf(a1[rq * 4 + 1], 0.f);
          ps1 = pk_fma(m, (v2f){w1.x, w1.y}, ps1);
          m[0] = fmaxf(a1[rq * 4 + 2], 0.f); m[1] = fmaxf(a1[rq * 4 + 3], 0.f);
          ps1 = pk_fma(m, (v2f){w1.z, w1.w}, ps1);
        }
        float s = (ps0[0] + ps0[1]) + (ps1[0] + ps1[1]);
        sb[bt] = xor32_add(s);   // + lane^32: full 64-h sum for col b
      }
      res[f] = g ? sb[1] : sb[0];   // lane owns row rowb + l (bt == g)
    }
  }

  // ---- epilogue: one full 128B row per lane (+b2, +skip), fully coalesced ----
  const long row = rowb + l;
  const float4* fr = (const float4*)(ft + row * NF);
  const float4* bb = (const float4*)b2;
  float4* op = (float4*)(out + row * NF);
#pragma unroll
  for (int q = 0; q < 8; ++q) {
    float4 x = fr[q], bv = bb[q], o;
    o.x = res[q * 4 + 0] + bv.x + x.x;
    o.y = res[q * 4 + 1] + bv.y + x.y;
    o.z = res[q * 4 + 2] + bv.z + x.z;
    o.w = res[q * 4 + 3] + bv.w + x.w;
    op[q] = o;
  }
}

extern "C" void kernel_launch(void* const* d_in, const int* in_sizes, int n_in,
                              void* d_out, int out_size, void* d_ws, size_t ws_size,
                              hipStream_t stream) {
  const float* ft = (const float*)d_in[0];
  const float* at = (const float*)d_in[1];
  const float* W1 = (const float*)d_in[2];
  const float* b1 = (const float*)d_in[3];
  const float* W2 = (const float*)d_in[4];
  const float* b2 = (const float*)d_in[5];
  float* out = (float*)d_out;

  unsigned short* w1p = (unsigned short*)d_ws;                 // 192 KB
  float* w2p = (float*)((char*)d_ws + (1u << 18));             // 16 KB @ 256 KB

  pack_w1_kernel<<<384, 256, 0, stream>>>(W1, b1, w1p);
  pack_w2_kernel<<<16, 256, 0, stream>>>(W2, w2p);
  fused_mlp_kernel<<<B_TOTAL / 256, 256, 0, stream>>>(ft, at, w1p, w2p, b2, out);
}